// Round 1
// baseline (4632.990 us; speedup 1.0000x reference)
//
#include <hip/hip_runtime.h>

#define N_NODES 100000

// ---------------------------------------------------------------------------
// Scatter-add kernel: one thread per (edge, float4-chunk).
// CH = feature dim / 4.  Consecutive threads cover consecutive chunks of the
// same source row -> coalesced float4 gather.  Scatter via 4 fp32 atomics.
// Chunk 0's thread also bumps the per-destination edge count (layer 1 only).
// ---------------------------------------------------------------------------
template <int CH, bool DO_CNT>
__global__ __launch_bounds__(256) void scatter_add_kernel(
    const float* __restrict__ x, const int* __restrict__ src,
    const int* __restrict__ dst, float* __restrict__ agg,
    float* __restrict__ cnt, int n_edges) {
  int gid = blockIdx.x * blockDim.x + threadIdx.x;
  int e = gid / CH;   // CH is a power of two -> shift
  int c = gid % CH;
  if (e >= n_edges) return;
  int s = src[e];
  int t = dst[e];
  float4 v = ((const float4*)x)[(long)s * CH + c];
  float* a = agg + ((long)t * CH + c) * 4;
  atomicAdd(a + 0, v.x);
  atomicAdd(a + 1, v.y);
  atomicAdd(a + 2, v.z);
  atomicAdd(a + 3, v.w);
  if (DO_CNT && c == 0) atomicAdd(&cnt[t], 1.0f);
}

// ---------------------------------------------------------------------------
// Node update: out[n,j] = act( (agg[n,:]/max(cnt,1)) @ wl  + b + xin[n,:] @ wr )
// Block = NPB nodes x DOUT threads.  x/mean rows staged in LDS; weight reads
// are coalesced over j and L2-resident (wl,wr are 32 KB each).
// ---------------------------------------------------------------------------
template <int DIN, int DOUT, int NPB, bool RELU>
__global__ __launch_bounds__(NPB * DOUT) void node_update_kernel(
    const float* __restrict__ xin, const float* __restrict__ agg,
    const float* __restrict__ cnt, const float* __restrict__ wl,
    const float* __restrict__ bias, const float* __restrict__ wr,
    float* __restrict__ out) {
  __shared__ float sx[NPB][DIN];
  __shared__ float sm[NPB][DIN];
  int node0 = blockIdx.x * NPB;
  // cooperative stage of x rows and mean rows
  for (int i = threadIdx.x; i < NPB * DIN; i += NPB * DOUT) {
    int n = i / DIN;
    int k = i % DIN;
    int node = node0 + n;
    if (node < N_NODES) {
      long idx = (long)node * DIN + k;
      float c = cnt[node];
      sx[n][k] = xin[idx];
      sm[n][k] = agg[idx] / fmaxf(c, 1.0f);
    }
  }
  __syncthreads();
  int nl = threadIdx.x / DOUT;
  int j = threadIdx.x % DOUT;
  int node = node0 + nl;
  if (node >= N_NODES) return;
  float acc = bias[j];
  #pragma unroll 8
  for (int k = 0; k < DIN; ++k) {
    acc += sm[nl][k] * wl[k * DOUT + j] + sx[nl][k] * wr[k * DOUT + j];
  }
  if (RELU) acc = fmaxf(acc, 0.0f);
  out[(long)node * DOUT + j] = acc;
}

extern "C" void kernel_launch(void* const* d_in, const int* in_sizes, int n_in,
                              void* d_out, int out_size, void* d_ws, size_t ws_size,
                              hipStream_t stream) {
  const float* x    = (const float*)d_in[0];
  const int*   ei   = (const int*)d_in[1];
  const float* w1_l = (const float*)d_in[2];
  const float* b1   = (const float*)d_in[3];
  const float* w1_r = (const float*)d_in[4];
  const float* w2_l = (const float*)d_in[5];
  const float* b2   = (const float*)d_in[6];
  const float* w2_r = (const float*)d_in[7];
  float* out = (float*)d_out;

  const int E = in_sizes[1] / 2;
  const int* src = ei;
  const int* dst = ei + E;

  // workspace layout
  float* agg = (float*)d_ws;                       // N*128 floats (reused as agg2)
  float* h   = agg + (long)N_NODES * 128;          // N*64 floats
  float* cnt = h + (long)N_NODES * 64;             // N floats

  // ---- Layer 1 ----
  hipMemsetAsync(agg, 0, (size_t)N_NODES * 128 * sizeof(float), stream);
  hipMemsetAsync(cnt, 0, (size_t)N_NODES * sizeof(float), stream);

  {
    long total = (long)E * 32;  // 32 float4-chunks per edge (d=128)
    int blocks = (int)((total + 255) / 256);
    scatter_add_kernel<32, true><<<blocks, 256, 0, stream>>>(x, src, dst, agg, cnt, E);
  }
  {
    int blocks = (N_NODES + 3) / 4;  // 4 nodes/block x 64 threads
    node_update_kernel<128, 64, 4, true><<<blocks, 256, 0, stream>>>(
        x, agg, cnt, w1_l, b1, w1_r, h);
  }

  // ---- Layer 2 ----
  hipMemsetAsync(agg, 0, (size_t)N_NODES * 64 * sizeof(float), stream);
  {
    long total = (long)E * 16;  // 16 float4-chunks per edge (d=64)
    int blocks = (int)((total + 255) / 256);
    scatter_add_kernel<16, false><<<blocks, 256, 0, stream>>>(h, src, dst, agg, nullptr, E);
  }
  {
    int blocks = (N_NODES + 1) / 2;  // 2 nodes/block x 128 threads
    node_update_kernel<64, 128, 2, false><<<blocks, 256, 0, stream>>>(
        h, agg, cnt, w2_l, b2, w2_r, out);
  }
}

// Round 2
// 871.459 us; speedup vs baseline: 5.3164x; 5.3164x over previous
//
#include <hip/hip_runtime.h>

#define N_NODES 100000
#define SCAN_NB 391   // ceil(100000/256)

// ---------------------------------------------------------------------------
// CSR build: degree histogram -> exclusive scan -> cursor scatter.
// Only ~3.2M int atomics total (vs 307M fp32 atomics in the scatter version).
// ---------------------------------------------------------------------------
__global__ __launch_bounds__(256) void degree_kernel(
    const int* __restrict__ dst, int* __restrict__ deg, int n_edges) {
  int e = blockIdx.x * 256 + threadIdx.x;
  if (e < n_edges) atomicAdd(&deg[dst[e]], 1);
}

__global__ __launch_bounds__(256) void block_sums_kernel(
    const int* __restrict__ deg, int* __restrict__ partials, int n) {
  int i = blockIdx.x * 256 + threadIdx.x;
  int v = (i < n) ? deg[i] : 0;
  #pragma unroll
  for (int off = 32; off > 0; off >>= 1) v += __shfl_down(v, off, 64);
  __shared__ int s[4];
  if ((threadIdx.x & 63) == 0) s[threadIdx.x >> 6] = v;
  __syncthreads();
  if (threadIdx.x == 0) partials[blockIdx.x] = s[0] + s[1] + s[2] + s[3];
}

// single block, 512 threads; turns partials[] into its exclusive prefix sum
__global__ __launch_bounds__(512) void scan_partials_kernel(int* partials, int nb) {
  __shared__ int s[512];
  int t = threadIdx.x;
  s[t] = (t < nb) ? partials[t] : 0;
  __syncthreads();
  for (int off = 1; off < 512; off <<= 1) {
    int u = (t >= off) ? s[t - off] : 0;
    __syncthreads();
    s[t] += u;
    __syncthreads();
  }
  if (t < nb) partials[t] = (t == 0) ? 0 : s[t - 1];
}

__global__ __launch_bounds__(256) void final_scan_kernel(
    const int* __restrict__ deg, const int* __restrict__ partials,
    int* __restrict__ offsets, int* __restrict__ cursor, int n, int n_edges) {
  __shared__ int s[256];
  int t = threadIdx.x;
  int i = blockIdx.x * 256 + t;
  int v = (i < n) ? deg[i] : 0;
  s[t] = v;
  __syncthreads();
  for (int off = 1; off < 256; off <<= 1) {
    int u = (t >= off) ? s[t - off] : 0;
    __syncthreads();
    s[t] += u;
    __syncthreads();
  }
  int excl = s[t] - v + partials[blockIdx.x];
  if (i < n) { offsets[i] = excl; cursor[i] = excl; }
  if (i == 0) offsets[n] = n_edges;
}

__global__ __launch_bounds__(256) void csr_scatter_kernel(
    const int* __restrict__ src, const int* __restrict__ dst,
    int* __restrict__ cursor, int* __restrict__ src_sorted, int n_edges) {
  int e = blockIdx.x * 256 + threadIdx.x;
  if (e < n_edges) {
    int pos = atomicAdd(&cursor[dst[e]], 1);
    src_sorted[pos] = src[e];
  }
}

// ---------------------------------------------------------------------------
// Gather aggregation, d=64: one wave per node, lane = feature.  Each edge is a
// fully-coalesced 256B row read (y is 25.6 MB -> L2/L3-resident).  Single
// write per node, no atomics, no zero-init needed.
// ---------------------------------------------------------------------------
__global__ __launch_bounds__(256) void aggregate64_kernel(
    const float* __restrict__ y, const int* __restrict__ offsets,
    const int* __restrict__ src_sorted, float* __restrict__ agg, int n_nodes) {
  int wave = (blockIdx.x * 256 + threadIdx.x) >> 6;
  int lane = threadIdx.x & 63;
  if (wave >= n_nodes) return;
  int beg = offsets[wave];
  int end = offsets[wave + 1];
  float acc = 0.f;
  int e = beg;
  for (; e + 1 < end; e += 2) {   // 2 independent loads per iter for ILP
    int s0 = src_sorted[e];
    int s1 = src_sorted[e + 1];
    float v0 = y[(long)s0 * 64 + lane];
    float v1 = y[(long)s1 * 64 + lane];
    acc += v0 + v1;
  }
  if (e < end) acc += y[(long)src_sorted[e] * 64 + lane];
  agg[(long)wave * 64 + lane] = acc;
}

// ---------------------------------------------------------------------------
// Dense per-node kernels.  Block = NPB nodes x DOUT threads, rows in LDS.
// ---------------------------------------------------------------------------

// y[n,:] = x[n,:] @ w   (pre-transform so aggregation runs in 64-dim)
template <int DIN, int DOUT, int NPB>
__global__ __launch_bounds__(NPB * DOUT) void transform_kernel(
    const float* __restrict__ xin, const float* __restrict__ w,
    float* __restrict__ y, int n_nodes) {
  __shared__ float sx[NPB][DIN];
  int node0 = blockIdx.x * NPB;
  for (int i = threadIdx.x; i < NPB * DIN; i += NPB * DOUT) {
    int n = i / DIN, k = i % DIN;
    if (node0 + n < n_nodes) sx[n][k] = xin[(long)(node0 + n) * DIN + k];
  }
  __syncthreads();
  int nl = threadIdx.x / DOUT, j = threadIdx.x % DOUT;
  int node = node0 + nl;
  if (node >= n_nodes) return;
  float acc = 0.f;
  #pragma unroll 8
  for (int k = 0; k < DIN; ++k) acc += sx[nl][k] * w[k * DOUT + j];
  y[(long)node * DOUT + j] = acc;
}

// h[n,:] = relu(agg[n,:]/max(deg,1) + b + x[n,:] @ wr)   (agg already in DOUT dim)
template <int DIN, int DOUT, int NPB>
__global__ __launch_bounds__(NPB * DOUT) void update1_kernel(
    const float* __restrict__ xin, const float* __restrict__ agg,
    const int* __restrict__ deg, const float* __restrict__ wr,
    const float* __restrict__ bias, float* __restrict__ h, int n_nodes) {
  __shared__ float sx[NPB][DIN];
  int node0 = blockIdx.x * NPB;
  for (int i = threadIdx.x; i < NPB * DIN; i += NPB * DOUT) {
    int n = i / DIN, k = i % DIN;
    if (node0 + n < n_nodes) sx[n][k] = xin[(long)(node0 + n) * DIN + k];
  }
  __syncthreads();
  int nl = threadIdx.x / DOUT, j = threadIdx.x % DOUT;
  int node = node0 + nl;
  if (node >= n_nodes) return;
  float inv = 1.f / fmaxf((float)deg[node], 1.f);
  float acc = agg[(long)node * DOUT + j] * inv + bias[j];
  #pragma unroll 8
  for (int k = 0; k < DIN; ++k) acc += sx[nl][k] * wr[k * DOUT + j];
  h[(long)node * DOUT + j] = fmaxf(acc, 0.f);
}

// out[n,:] = (agg[n,:]/max(deg,1)) @ wl + b + h[n,:] @ wr
template <int DIN, int DOUT, int NPB>
__global__ __launch_bounds__(NPB * DOUT) void update2_kernel(
    const float* __restrict__ hin, const float* __restrict__ agg,
    const int* __restrict__ deg, const float* __restrict__ wl,
    const float* __restrict__ bias, const float* __restrict__ wr,
    float* __restrict__ out, int n_nodes) {
  __shared__ float sh[NPB][DIN];
  __shared__ float sm[NPB][DIN];
  int node0 = blockIdx.x * NPB;
  for (int i = threadIdx.x; i < NPB * DIN; i += NPB * DOUT) {
    int n = i / DIN, k = i % DIN;
    int node = node0 + n;
    if (node < n_nodes) {
      long idx = (long)node * DIN + k;
      float inv = 1.f / fmaxf((float)deg[node], 1.f);
      sh[n][k] = hin[idx];
      sm[n][k] = agg[idx] * inv;
    }
  }
  __syncthreads();
  int nl = threadIdx.x / DOUT, j = threadIdx.x % DOUT;
  int node = node0 + nl;
  if (node >= n_nodes) return;
  float acc = bias[j];
  #pragma unroll 8
  for (int k = 0; k < DIN; ++k)
    acc += sm[nl][k] * wl[k * DOUT + j] + sh[nl][k] * wr[k * DOUT + j];
  out[(long)node * DOUT + j] = acc;
}

extern "C" void kernel_launch(void* const* d_in, const int* in_sizes, int n_in,
                              void* d_out, int out_size, void* d_ws, size_t ws_size,
                              hipStream_t stream) {
  const float* x    = (const float*)d_in[0];
  const int*   ei   = (const int*)d_in[1];
  const float* w1_l = (const float*)d_in[2];
  const float* b1   = (const float*)d_in[3];
  const float* w1_r = (const float*)d_in[4];
  const float* w2_l = (const float*)d_in[5];
  const float* b2   = (const float*)d_in[6];
  const float* w2_r = (const float*)d_in[7];
  float* out = (float*)d_out;

  const int E = in_sizes[1] / 2;
  const int* src = ei;
  const int* dst = ei + E;

  // ---- workspace layout ----
  float* bufA = (float*)d_ws;                      // N*64: y1, then reused as h
  float* bufB = bufA + (long)N_NODES * 64;         // N*64: agg (both layers)
  int* deg        = (int*)(bufB + (long)N_NODES * 64);
  int* partials   = deg + N_NODES;                 // 512
  int* offsets    = partials + 512;                // N+1
  int* cursor     = offsets + N_NODES + 1;         // N
  int* src_sorted = cursor + N_NODES;              // E

  int eb = (E + 255) / 256;
  int nb = SCAN_NB;

  // ---- CSR build ----
  hipMemsetAsync(deg, 0, (size_t)N_NODES * sizeof(int), stream);
  degree_kernel<<<eb, 256, 0, stream>>>(dst, deg, E);
  block_sums_kernel<<<nb, 256, 0, stream>>>(deg, partials, N_NODES);
  scan_partials_kernel<<<1, 512, 0, stream>>>(partials, nb);
  final_scan_kernel<<<nb, 256, 0, stream>>>(deg, partials, offsets, cursor,
                                            N_NODES, E);
  csr_scatter_kernel<<<eb, 256, 0, stream>>>(src, dst, cursor, src_sorted, E);

  // ---- Layer 1 ----
  // y1 = x @ w1_l  (pre-transform: mean(x_j) @ w = mean(x_j @ w))
  transform_kernel<128, 64, 4><<<(N_NODES + 3) / 4, 256, 0, stream>>>(
      x, w1_l, bufA, N_NODES);
  // agg = sum_{j in N(i)} y1_j
  aggregate64_kernel<<<(N_NODES + 3) / 4, 256, 0, stream>>>(
      bufA, offsets, src_sorted, bufB, N_NODES);
  // h = relu(agg/cnt + b1 + x @ w1_r)   (overwrites y1 -- y1 is dead)
  update1_kernel<128, 64, 4><<<(N_NODES + 3) / 4, 256, 0, stream>>>(
      x, bufB, deg, w1_r, b1, bufA, N_NODES);

  // ---- Layer 2 ----
  // agg = sum_{j in N(i)} h_j
  aggregate64_kernel<<<(N_NODES + 3) / 4, 256, 0, stream>>>(
      bufA, offsets, src_sorted, bufB, N_NODES);
  // out = (agg/cnt) @ w2_l + b2 + h @ w2_r
  update2_kernel<64, 128, 2><<<(N_NODES + 1) / 2, 256, 0, stream>>>(
      bufA, bufB, deg, w2_l, b2, w2_r, out, N_NODES);
}

// Round 3
// 564.954 us; speedup vs baseline: 8.2006x; 1.5425x over previous
//
#include <hip/hip_runtime.h>

#define N_NODES 100000
#define SCAN_NB 391   // ceil(100000/256)

// ===========================================================================
// CSR build: degree histogram -> exclusive scan -> cursor scatter.
// ===========================================================================
__global__ __launch_bounds__(256) void degree_kernel(
    const int* __restrict__ dst, int* __restrict__ deg, int n_edges) {
  int e = blockIdx.x * 256 + threadIdx.x;
  if (e < n_edges) atomicAdd(&deg[dst[e]], 1);
}

__global__ __launch_bounds__(256) void block_sums_kernel(
    const int* __restrict__ deg, int* __restrict__ partials, int n) {
  int i = blockIdx.x * 256 + threadIdx.x;
  int v = (i < n) ? deg[i] : 0;
  #pragma unroll
  for (int off = 32; off > 0; off >>= 1) v += __shfl_down(v, off, 64);
  __shared__ int s[4];
  if ((threadIdx.x & 63) == 0) s[threadIdx.x >> 6] = v;
  __syncthreads();
  if (threadIdx.x == 0) partials[blockIdx.x] = s[0] + s[1] + s[2] + s[3];
}

__global__ __launch_bounds__(512) void scan_partials_kernel(int* partials, int nb) {
  __shared__ int s[512];
  int t = threadIdx.x;
  s[t] = (t < nb) ? partials[t] : 0;
  __syncthreads();
  for (int off = 1; off < 512; off <<= 1) {
    int u = (t >= off) ? s[t - off] : 0;
    __syncthreads();
    s[t] += u;
    __syncthreads();
  }
  if (t < nb) partials[t] = (t == 0) ? 0 : s[t - 1];
}

__global__ __launch_bounds__(256) void final_scan_kernel(
    const int* __restrict__ deg, const int* __restrict__ partials,
    int* __restrict__ offsets, int* __restrict__ cursor, int n, int n_edges) {
  __shared__ int s[256];
  int t = threadIdx.x;
  int i = blockIdx.x * 256 + t;
  int v = (i < n) ? deg[i] : 0;
  s[t] = v;
  __syncthreads();
  for (int off = 1; off < 256; off <<= 1) {
    int u = (t >= off) ? s[t - off] : 0;
    __syncthreads();
    s[t] += u;
    __syncthreads();
  }
  int excl = s[t] - v + partials[blockIdx.x];
  if (i < n) { offsets[i] = excl; cursor[i] = excl; }
  if (i == 0) offsets[n] = n_edges;
}

__global__ __launch_bounds__(256) void csr_scatter_kernel(
    const int* __restrict__ src, const int* __restrict__ dst,
    int* __restrict__ cursor, int* __restrict__ src_sorted, int n_edges) {
  int e = blockIdx.x * 256 + threadIdx.x;
  if (e < n_edges) {
    int pos = atomicAdd(&cursor[dst[e]], 1);
    src_sorted[pos] = src[e];
  }
}

// ===========================================================================
// Register-tiled fp32 GEMM: Y[M][128] = A[M][128] @ W[128][128] (+bias).
// Block tile: 64 nodes x 128 cols.  Thread tile: 4 nodes x (4+4) cols.
// A-tile staged in LDS (stride 132: 2-way bank alias = free).  B read from
// global (L2-resident, coalesced float4, 4-way broadcast across tn).
//  STACKED=false: W = [B0 | B1] side by side (row stride 64 each)   -> layer 1
//  STACKED=true : W = [B0 ; B1] stacked on k (row stride 128 each)  -> layer 2
// ===========================================================================
template <int KROWS>
__device__ __forceinline__ void gemm_inner(
    const float* __restrict__ As, int arow0,
    const float* __restrict__ bpL, const float* __restrict__ bpH,
    int bs, int kbase, float acc[4][8]) {
  #pragma unroll 2
  for (int k4 = 0; k4 < KROWS; k4 += 4) {
    float a_[4][4];
    #pragma unroll
    for (int i = 0; i < 4; ++i) {
      float4 v = *(const float4*)&As[(arow0 + i) * 132 + kbase + k4];
      a_[i][0] = v.x; a_[i][1] = v.y; a_[i][2] = v.z; a_[i][3] = v.w;
    }
    #pragma unroll
    for (int kk = 0; kk < 4; ++kk) {
      float4 bL = *(const float4*)&bpL[(long)(k4 + kk) * bs];
      float4 bH = *(const float4*)&bpH[(long)(k4 + kk) * bs];
      #pragma unroll
      for (int i = 0; i < 4; ++i) {
        float s = a_[i][kk];
        acc[i][0] += s * bL.x; acc[i][1] += s * bL.y;
        acc[i][2] += s * bL.z; acc[i][3] += s * bL.w;
        acc[i][4] += s * bH.x; acc[i][5] += s * bH.y;
        acc[i][6] += s * bH.z; acc[i][7] += s * bH.w;
      }
    }
  }
}

template <bool STACKED>
__global__ __launch_bounds__(256) void gemm_kernel(
    const float* __restrict__ A, const float* __restrict__ B0,
    const float* __restrict__ B1, const float* __restrict__ biasL,
    const float* __restrict__ biasH, float* __restrict__ Y, int M) {
  __shared__ float As[64 * 132];
  int node0 = blockIdx.x * 64;
  for (int t = threadIdx.x; t < 2048; t += 256) {
    int r = t >> 5, c4 = (t & 31) << 2;
    float4 v = make_float4(0.f, 0.f, 0.f, 0.f);
    if (node0 + r < M) v = *(const float4*)&A[(long)(node0 + r) * 128 + c4];
    *(float4*)&As[r * 132 + c4] = v;
  }
  __syncthreads();
  int tj = threadIdx.x & 15, tn = threadIdx.x >> 4;
  int c = tj * 4;
  int arow0 = tn * 4;
  float acc[4][8] = {};
  if (STACKED) {
    gemm_inner<64>(As, arow0, B0 + c, B0 + c + 64, 128, 0, acc);
    gemm_inner<64>(As, arow0, B1 + c, B1 + c + 64, 128, 64, acc);
  } else {
    gemm_inner<128>(As, arow0, B0 + c, B1 + c, 64, 0, acc);
  }
  float bL[4] = {0.f, 0.f, 0.f, 0.f}, bH[4] = {0.f, 0.f, 0.f, 0.f};
  if (biasL) { bL[0] = biasL[c]; bL[1] = biasL[c + 1]; bL[2] = biasL[c + 2]; bL[3] = biasL[c + 3]; }
  if (biasH) { bH[0] = biasH[c]; bH[1] = biasH[c + 1]; bH[2] = biasH[c + 2]; bH[3] = biasH[c + 3]; }
  #pragma unroll
  for (int i = 0; i < 4; ++i) {
    int node = node0 + arow0 + i;
    if (node >= M) continue;
    float4 o0 = make_float4(acc[i][0] + bL[0], acc[i][1] + bL[1],
                            acc[i][2] + bL[2], acc[i][3] + bL[3]);
    float4 o1 = make_float4(acc[i][4] + bH[0], acc[i][5] + bH[1],
                            acc[i][6] + bH[2], acc[i][7] + bH[3]);
    *(float4*)&Y[(long)node * 128 + c] = o0;
    *(float4*)&Y[(long)node * 128 + 64 + c] = o1;
  }
}

// ===========================================================================
// Gather-mean aggregation over 64 features of the 128-wide Z buffer.
// One wave per node; 16 lanes x float4 per edge row -> 4 edges in flight.
// Scales by 1/max(deg,1) (deg from CSR offsets).  FUSE_RELU: h = relu(mean +
// Z[n][OUT_COL..]) written in place (layer-1 epilogue).  Column-disjoint from
// cross-row reads -> race-free.
// ===========================================================================
template <bool FUSE_RELU, int IN_COL, int OUT_COL>
__global__ __launch_bounds__(256) void aggregate_kernel(
    float* __restrict__ Z, const int* __restrict__ offsets,
    const int* __restrict__ src_sorted, int n_nodes) {
  int wave = (blockIdx.x * 256 + threadIdx.x) >> 6;
  int lane = threadIdx.x & 63;
  if (wave >= n_nodes) return;
  int g = lane >> 4, l = lane & 15;
  int beg = offsets[wave], end = offsets[wave + 1];
  float4 acc = make_float4(0.f, 0.f, 0.f, 0.f);
  for (int e = beg + g; e < end; e += 4) {
    int s = src_sorted[e];
    float4 v = *(const float4*)&Z[(long)s * 128 + IN_COL + l * 4];
    acc.x += v.x; acc.y += v.y; acc.z += v.z; acc.w += v.w;
  }
  // combine the 4 lane-groups
  acc.x += __shfl_xor(acc.x, 16, 64); acc.y += __shfl_xor(acc.y, 16, 64);
  acc.z += __shfl_xor(acc.z, 16, 64); acc.w += __shfl_xor(acc.w, 16, 64);
  acc.x += __shfl_xor(acc.x, 32, 64); acc.y += __shfl_xor(acc.y, 32, 64);
  acc.z += __shfl_xor(acc.z, 32, 64); acc.w += __shfl_xor(acc.w, 32, 64);
  if (g == 0) {
    float inv = 1.f / fmaxf((float)(end - beg), 1.f);
    float4 r = make_float4(acc.x * inv, acc.y * inv, acc.z * inv, acc.w * inv);
    float* outp = &Z[(long)wave * 128 + OUT_COL + l * 4];
    if (FUSE_RELU) {
      float4 z = *(const float4*)outp;
      r.x = fmaxf(r.x + z.x, 0.f); r.y = fmaxf(r.y + z.y, 0.f);
      r.z = fmaxf(r.z + z.z, 0.f); r.w = fmaxf(r.w + z.w, 0.f);
    }
    *(float4*)outp = r;
  }
}

extern "C" void kernel_launch(void* const* d_in, const int* in_sizes, int n_in,
                              void* d_out, int out_size, void* d_ws, size_t ws_size,
                              hipStream_t stream) {
  const float* x    = (const float*)d_in[0];
  const int*   ei   = (const int*)d_in[1];
  const float* w1_l = (const float*)d_in[2];
  const float* b1   = (const float*)d_in[3];
  const float* w1_r = (const float*)d_in[4];
  const float* w2_l = (const float*)d_in[5];
  const float* b2   = (const float*)d_in[6];
  const float* w2_r = (const float*)d_in[7];
  float* out = (float*)d_out;

  const int E = in_sizes[1] / 2;
  const int* src = ei;
  const int* dst = ei + E;

  // ---- workspace layout (~59 MB) ----
  float* Z = (float*)d_ws;                         // [N][128] fused buffer
  int* deg        = (int*)(Z + (long)N_NODES * 128);
  int* partials   = deg + N_NODES;                 // 512
  int* offsets    = partials + 512;                // N+1
  int* cursor     = offsets + N_NODES + 1;         // N
  int* src_sorted = cursor + N_NODES;              // E

  int eb = (E + 255) / 256;

  // ---- CSR build ----
  hipMemsetAsync(deg, 0, (size_t)N_NODES * sizeof(int), stream);
  degree_kernel<<<eb, 256, 0, stream>>>(dst, deg, E);
  block_sums_kernel<<<SCAN_NB, 256, 0, stream>>>(deg, partials, N_NODES);
  scan_partials_kernel<<<1, 512, 0, stream>>>(partials, SCAN_NB);
  final_scan_kernel<<<SCAN_NB, 256, 0, stream>>>(deg, partials, offsets, cursor,
                                                 N_NODES, E);
  csr_scatter_kernel<<<eb, 256, 0, stream>>>(src, dst, cursor, src_sorted, E);

  int gemm_blocks = (N_NODES + 63) / 64;
  int agg_blocks = (N_NODES + 3) / 4;

  // ---- Layer 1: Z[:,0:64] = x@w1_l ; Z[:,64:128] = x@w1_r + b1 ----
  gemm_kernel<false><<<gemm_blocks, 256, 0, stream>>>(
      x, w1_l, w1_r, nullptr, b1, Z, N_NODES);
  // h = relu(mean(y1) + z1), in place into Z[:,64:128]
  aggregate_kernel<true, 0, 64><<<agg_blocks, 256, 0, stream>>>(
      Z, offsets, src_sorted, N_NODES);

  // ---- Layer 2: mean2 into Z[:,0:64], then out = Z @ [w2_l; w2_r] + b2 ----
  aggregate_kernel<false, 64, 0><<<agg_blocks, 256, 0, stream>>>(
      Z, offsets, src_sorted, N_NODES);
  gemm_kernel<true><<<gemm_blocks, 256, 0, stream>>>(
      Z, w2_l, w2_r, b2, b2 + 64, out, N_NODES);
}

// Round 4
// 480.688 us; speedup vs baseline: 9.6382x; 1.1753x over previous
//
#include <hip/hip_runtime.h>

#define N_NODES 100000
#define SCAN_NB 391      // ceil(100000/256)
#define NBUCK   782      // ceil(100000/128) buckets of 128 nodes
#define P1TILE  8192     // edges per phase-1 block
#define MAXB    4096     // phase-2 LDS capacity (avg bucket = 2048 edges)

// ===========================================================================
// Degree histogram -> exclusive scan  (node-level CSR offsets)
// ===========================================================================
__global__ __launch_bounds__(256) void degree_kernel(
    const int* __restrict__ dst, int* __restrict__ deg, int n_edges) {
  int e = blockIdx.x * 256 + threadIdx.x;
  if (e < n_edges) atomicAdd(&deg[dst[e]], 1);
}

__global__ __launch_bounds__(256) void block_sums_kernel(
    const int* __restrict__ deg, int* __restrict__ partials, int n) {
  int i = blockIdx.x * 256 + threadIdx.x;
  int v = (i < n) ? deg[i] : 0;
  #pragma unroll
  for (int off = 32; off > 0; off >>= 1) v += __shfl_down(v, off, 64);
  __shared__ int s[4];
  if ((threadIdx.x & 63) == 0) s[threadIdx.x >> 6] = v;
  __syncthreads();
  if (threadIdx.x == 0) partials[blockIdx.x] = s[0] + s[1] + s[2] + s[3];
}

__global__ __launch_bounds__(512) void scan_partials_kernel(int* partials, int nb) {
  __shared__ int s[512];
  int t = threadIdx.x;
  s[t] = (t < nb) ? partials[t] : 0;
  __syncthreads();
  for (int off = 1; off < 512; off <<= 1) {
    int u = (t >= off) ? s[t - off] : 0;
    __syncthreads();
    s[t] += u;
    __syncthreads();
  }
  if (t < nb) partials[t] = (t == 0) ? 0 : s[t - 1];
}

__global__ __launch_bounds__(256) void final_scan_kernel(
    const int* __restrict__ deg, const int* __restrict__ partials,
    int* __restrict__ offsets, int n, int n_edges) {
  __shared__ int s[256];
  int t = threadIdx.x;
  int i = blockIdx.x * 256 + t;
  int v = (i < n) ? deg[i] : 0;
  s[t] = v;
  __syncthreads();
  for (int off = 1; off < 256; off <<= 1) {
    int u = (t >= off) ? s[t - off] : 0;
    __syncthreads();
    s[t] += u;
    __syncthreads();
  }
  int excl = s[t] - v + partials[blockIdx.x];
  if (i < n) offsets[i] = excl;
  if (i == 0) offsets[n] = n_edges;
}

// bucket b's edge region starts at offsets[b*128]
__global__ __launch_bounds__(256) void bucket_init_kernel(
    const int* __restrict__ offsets, int* __restrict__ bucket_cursor) {
  int b = blockIdx.x * 256 + threadIdx.x;
  if (b < NBUCK) bucket_cursor[b] = offsets[b << 7];
}

// ===========================================================================
// Phase 1: partition (src,dst) pairs into 782 dst-buckets (128 nodes each).
// LDS histogram + scan + reorder per 8192-edge tile so same-bucket pairs
// leave the block as contiguous runs (~84 B) -> no 16x write amplification.
// ===========================================================================
__global__ __launch_bounds__(256) void bucket_partition_kernel(
    const int* __restrict__ src, const int* __restrict__ dst,
    int* __restrict__ bucket_cursor, int2* __restrict__ pairs, int n_edges) {
  __shared__ int hist[NBUCK];
  __shared__ int scan_[NBUCK];
  __shared__ int gbase[NBUCK];
  __shared__ int tmp[256];
  __shared__ int2 sorted[P1TILE];
  int t = threadIdx.x;
  long e0 = (long)blockIdx.x * P1TILE;
  int n = (int)min((long)P1TILE, (long)n_edges - e0);

  for (int b = t; b < NBUCK; b += 256) hist[b] = 0;
  __syncthreads();
  for (int i = t; i < n; i += 256) atomicAdd(&hist[dst[e0 + i] >> 7], 1);
  __syncthreads();

  // exclusive scan of hist[0..NBUCK): thread t covers buckets 4t..4t+3
  int loc[4];
  int s = 0;
  #pragma unroll
  for (int j = 0; j < 4; ++j) {
    int idx = 4 * t + j;
    loc[j] = s;
    s += (idx < NBUCK) ? hist[idx] : 0;
  }
  tmp[t] = s;
  __syncthreads();
  for (int off = 1; off < 256; off <<= 1) {
    int u = (t >= off) ? tmp[t - off] : 0;
    __syncthreads();
    tmp[t] += u;
    __syncthreads();
  }
  int excl = tmp[t] - s;
  #pragma unroll
  for (int j = 0; j < 4; ++j) {
    int idx = 4 * t + j;
    if (idx < NBUCK) scan_[idx] = excl + loc[j];
  }
  __syncthreads();

  // reserve global space per bucket; repurpose hist as local rank cursor
  for (int b = t; b < NBUCK; b += 256) {
    int c = hist[b];
    gbase[b] = c ? atomicAdd(&bucket_cursor[b], c) : 0;
    hist[b] = scan_[b];
  }
  __syncthreads();

  // reorder tile into LDS, grouped by bucket
  for (int i = t; i < n; i += 256) {
    int sv = src[e0 + i];
    int dv = dst[e0 + i];
    int r = atomicAdd(&hist[dv >> 7], 1);   // LDS atomic
    sorted[r] = make_int2(sv, dv);
  }
  __syncthreads();

  // grouped write-out: consecutive i within a bucket -> consecutive global
  for (int i = t; i < n; i += 256) {
    int2 p = sorted[i];
    int b = p.y >> 7;
    pairs[gbase[b] + (i - scan_[b])] = p;
  }
}

// ===========================================================================
// Phase 2: within each bucket, sort src values by exact dst node via LDS
// cursors + LDS staging, then stream out fully coalesced.
// ===========================================================================
__global__ __launch_bounds__(256) void bucket_to_csr_kernel(
    const int2* __restrict__ pairs, const int* __restrict__ offsets,
    int* __restrict__ src_sorted, int n_nodes) {
  __shared__ int lcur[128];
  __shared__ int lout[MAXB];
  int b = blockIdx.x;
  int node0 = b << 7;
  int nend = min(node0 + 128, n_nodes);
  int t = threadIdx.x;
  int ebeg = offsets[node0];
  int eend = offsets[nend];
  int m = eend - ebeg;
  if (t < 128) {
    int node = node0 + t;
    lcur[t] = (node < n_nodes ? offsets[node] : eend) - ebeg;
  }
  __syncthreads();
  if (m <= MAXB) {
    for (int i = t; i < m; i += 256) {
      int2 p = pairs[ebeg + i];
      int r = atomicAdd(&lcur[p.y - node0], 1);  // LDS atomic
      lout[r] = p.x;
    }
    __syncthreads();
    for (int i = t; i < m; i += 256) src_sorted[ebeg + i] = lout[i];
  } else {  // overflow fallback (statistically never for this input)
    for (int i = t; i < m; i += 256) {
      int2 p = pairs[ebeg + i];
      int r = atomicAdd(&lcur[p.y - node0], 1);
      src_sorted[ebeg + r] = p.x;
    }
  }
}

// ===========================================================================
// Register-tiled fp32 GEMM: Y[M][128] = A[M][128] @ W[128][128] (+bias).
// Block tile: 64 nodes x 128 cols.  Thread tile: 4 nodes x (4+4) cols.
//  STACKED=false: W = [B0 | B1] side by side (row stride 64 each)   -> layer 1
//  STACKED=true : W = [B0 ; B1] stacked on k (row stride 128 each)  -> layer 2
// ===========================================================================
template <int KROWS>
__device__ __forceinline__ void gemm_inner(
    const float* __restrict__ As, int arow0,
    const float* __restrict__ bpL, const float* __restrict__ bpH,
    int bs, int kbase, float acc[4][8]) {
  #pragma unroll 2
  for (int k4 = 0; k4 < KROWS; k4 += 4) {
    float a_[4][4];
    #pragma unroll
    for (int i = 0; i < 4; ++i) {
      float4 v = *(const float4*)&As[(arow0 + i) * 132 + kbase + k4];
      a_[i][0] = v.x; a_[i][1] = v.y; a_[i][2] = v.z; a_[i][3] = v.w;
    }
    #pragma unroll
    for (int kk = 0; kk < 4; ++kk) {
      float4 bL = *(const float4*)&bpL[(long)(k4 + kk) * bs];
      float4 bH = *(const float4*)&bpH[(long)(k4 + kk) * bs];
      #pragma unroll
      for (int i = 0; i < 4; ++i) {
        float s = a_[i][kk];
        acc[i][0] += s * bL.x; acc[i][1] += s * bL.y;
        acc[i][2] += s * bL.z; acc[i][3] += s * bL.w;
        acc[i][4] += s * bH.x; acc[i][5] += s * bH.y;
        acc[i][6] += s * bH.z; acc[i][7] += s * bH.w;
      }
    }
  }
}

template <bool STACKED>
__global__ __launch_bounds__(256) void gemm_kernel(
    const float* __restrict__ A, const float* __restrict__ B0,
    const float* __restrict__ B1, const float* __restrict__ biasL,
    const float* __restrict__ biasH, float* __restrict__ Y, int M) {
  __shared__ float As[64 * 132];
  int node0 = blockIdx.x * 64;
  for (int t = threadIdx.x; t < 2048; t += 256) {
    int r = t >> 5, c4 = (t & 31) << 2;
    float4 v = make_float4(0.f, 0.f, 0.f, 0.f);
    if (node0 + r < M) v = *(const float4*)&A[(long)(node0 + r) * 128 + c4];
    *(float4*)&As[r * 132 + c4] = v;
  }
  __syncthreads();
  int tj = threadIdx.x & 15, tn = threadIdx.x >> 4;
  int c = tj * 4;
  int arow0 = tn * 4;
  float acc[4][8] = {};
  if (STACKED) {
    gemm_inner<64>(As, arow0, B0 + c, B0 + c + 64, 128, 0, acc);
    gemm_inner<64>(As, arow0, B1 + c, B1 + c + 64, 128, 64, acc);
  } else {
    gemm_inner<128>(As, arow0, B0 + c, B1 + c, 64, 0, acc);
  }
  float bL[4] = {0.f, 0.f, 0.f, 0.f}, bH[4] = {0.f, 0.f, 0.f, 0.f};
  if (biasL) { bL[0] = biasL[c]; bL[1] = biasL[c + 1]; bL[2] = biasL[c + 2]; bL[3] = biasL[c + 3]; }
  if (biasH) { bH[0] = biasH[c]; bH[1] = biasH[c + 1]; bH[2] = biasH[c + 2]; bH[3] = biasH[c + 3]; }
  #pragma unroll
  for (int i = 0; i < 4; ++i) {
    int node = node0 + arow0 + i;
    if (node >= M) continue;
    float4 o0 = make_float4(acc[i][0] + bL[0], acc[i][1] + bL[1],
                            acc[i][2] + bL[2], acc[i][3] + bL[3]);
    float4 o1 = make_float4(acc[i][4] + bH[0], acc[i][5] + bH[1],
                            acc[i][6] + bH[2], acc[i][7] + bH[3]);
    *(float4*)&Y[(long)node * 128 + c] = o0;
    *(float4*)&Y[(long)node * 128 + 64 + c] = o1;
  }
}

// ===========================================================================
// Gather-mean aggregation over 64 features of the 128-wide Z buffer.
// One wave per node; 16 lanes x float4, 4 edges in flight; shfl combine.
// ===========================================================================
template <bool FUSE_RELU, int IN_COL, int OUT_COL>
__global__ __launch_bounds__(256) void aggregate_kernel(
    float* __restrict__ Z, const int* __restrict__ offsets,
    const int* __restrict__ src_sorted, int n_nodes) {
  int wave = (blockIdx.x * 256 + threadIdx.x) >> 6;
  int lane = threadIdx.x & 63;
  if (wave >= n_nodes) return;
  int g = lane >> 4, l = lane & 15;
  int beg = offsets[wave], end = offsets[wave + 1];
  float4 acc = make_float4(0.f, 0.f, 0.f, 0.f);
  for (int e = beg + g; e < end; e += 4) {
    int s = src_sorted[e];
    float4 v = *(const float4*)&Z[(long)s * 128 + IN_COL + l * 4];
    acc.x += v.x; acc.y += v.y; acc.z += v.z; acc.w += v.w;
  }
  acc.x += __shfl_xor(acc.x, 16, 64); acc.y += __shfl_xor(acc.y, 16, 64);
  acc.z += __shfl_xor(acc.z, 16, 64); acc.w += __shfl_xor(acc.w, 16, 64);
  acc.x += __shfl_xor(acc.x, 32, 64); acc.y += __shfl_xor(acc.y, 32, 64);
  acc.z += __shfl_xor(acc.z, 32, 64); acc.w += __shfl_xor(acc.w, 32, 64);
  if (g == 0) {
    float inv = 1.f / fmaxf((float)(end - beg), 1.f);
    float4 r = make_float4(acc.x * inv, acc.y * inv, acc.z * inv, acc.w * inv);
    float* outp = &Z[(long)wave * 128 + OUT_COL + l * 4];
    if (FUSE_RELU) {
      float4 z = *(const float4*)outp;
      r.x = fmaxf(r.x + z.x, 0.f); r.y = fmaxf(r.y + z.y, 0.f);
      r.z = fmaxf(r.z + z.z, 0.f); r.w = fmaxf(r.w + z.w, 0.f);
    }
    *(float4*)outp = r;
  }
}

extern "C" void kernel_launch(void* const* d_in, const int* in_sizes, int n_in,
                              void* d_out, int out_size, void* d_ws, size_t ws_size,
                              hipStream_t stream) {
  const float* x    = (const float*)d_in[0];
  const int*   ei   = (const int*)d_in[1];
  const float* w1_l = (const float*)d_in[2];
  const float* b1   = (const float*)d_in[3];
  const float* w1_r = (const float*)d_in[4];
  const float* w2_l = (const float*)d_in[5];
  const float* b2   = (const float*)d_in[6];
  const float* w2_r = (const float*)d_in[7];
  float* out = (float*)d_out;

  const int E = in_sizes[1] / 2;
  const int* src = ei;
  const int* dst = ei + E;

  // ---- workspace layout (~71 MB) ----
  float* Z = (float*)d_ws;                         // [N][128] fused buffer
  int* deg           = (int*)(Z + (long)N_NODES * 128);
  int* partials      = deg + N_NODES;              // 512
  int* offsets       = partials + 512;             // N+1
  int* bucket_cursor = offsets + N_NODES + 1;      // NBUCK (+pad)
  int* src_sorted    = bucket_cursor + NBUCK + 2;  // E
  int2* pairs        = (int2*)(src_sorted + E);    // E int2  (16B-aligned: offset even)

  int eb = (E + 255) / 256;

  // ---- CSR build ----
  hipMemsetAsync(deg, 0, (size_t)N_NODES * sizeof(int), stream);
  degree_kernel<<<eb, 256, 0, stream>>>(dst, deg, E);
  block_sums_kernel<<<SCAN_NB, 256, 0, stream>>>(deg, partials, N_NODES);
  scan_partials_kernel<<<1, 512, 0, stream>>>(partials, SCAN_NB);
  final_scan_kernel<<<SCAN_NB, 256, 0, stream>>>(deg, partials, offsets,
                                                 N_NODES, E);
  bucket_init_kernel<<<(NBUCK + 255) / 256, 256, 0, stream>>>(offsets,
                                                              bucket_cursor);
  bucket_partition_kernel<<<(E + P1TILE - 1) / P1TILE, 256, 0, stream>>>(
      src, dst, bucket_cursor, pairs, E);
  bucket_to_csr_kernel<<<NBUCK, 256, 0, stream>>>(pairs, offsets, src_sorted,
                                                  N_NODES);

  int gemm_blocks = (N_NODES + 63) / 64;
  int agg_blocks = (N_NODES + 3) / 4;

  // ---- Layer 1: Z[:,0:64] = x@w1_l ; Z[:,64:128] = x@w1_r + b1 ----
  gemm_kernel<false><<<gemm_blocks, 256, 0, stream>>>(
      x, w1_l, w1_r, nullptr, b1, Z, N_NODES);
  aggregate_kernel<true, 0, 64><<<agg_blocks, 256, 0, stream>>>(
      Z, offsets, src_sorted, N_NODES);

  // ---- Layer 2: mean2 into Z[:,0:64], then out = Z @ [w2_l; w2_r] + b2 ----
  aggregate_kernel<false, 64, 0><<<agg_blocks, 256, 0, stream>>>(
      Z, offsets, src_sorted, N_NODES);
  gemm_kernel<true><<<gemm_blocks, 256, 0, stream>>>(
      Z, w2_l, w2_r, b2, b2 + 64, out, N_NODES);
}

// Round 5
// 364.205 us; speedup vs baseline: 12.7208x; 1.3198x over previous
//
#include <hip/hip_runtime.h>

#define N_NODES 100000
#define SCAN_NB 391      // ceil(100000/256)
#define NBUCK   782      // ceil(100000/128) buckets of 128 nodes
#define P1TILE  8192     // edges per phase-1 block
#define MAXB    4096     // phase-2 LDS capacity (avg bucket = 2048 edges)

typedef __bf16 bf16x8 __attribute__((ext_vector_type(8)));
typedef float floatx4 __attribute__((ext_vector_type(4)));

static __device__ __forceinline__ unsigned short f2bf(float f) {
  unsigned u = __float_as_uint(f);
  u += 0x7fff + ((u >> 16) & 1);   // round-to-nearest-even
  return (unsigned short)(u >> 16);
}

// ===========================================================================
// CSR build: degree -> scan -> bucketed two-phase sort (no write-amp).
// ===========================================================================
__global__ __launch_bounds__(256) void degree_kernel(
    const int* __restrict__ dst, int* __restrict__ deg, int n_edges) {
  int e = blockIdx.x * 256 + threadIdx.x;
  if (e < n_edges) atomicAdd(&deg[dst[e]], 1);
}

__global__ __launch_bounds__(256) void block_sums_kernel(
    const int* __restrict__ deg, int* __restrict__ partials, int n) {
  int i = blockIdx.x * 256 + threadIdx.x;
  int v = (i < n) ? deg[i] : 0;
  #pragma unroll
  for (int off = 32; off > 0; off >>= 1) v += __shfl_down(v, off, 64);
  __shared__ int s[4];
  if ((threadIdx.x & 63) == 0) s[threadIdx.x >> 6] = v;
  __syncthreads();
  if (threadIdx.x == 0) partials[blockIdx.x] = s[0] + s[1] + s[2] + s[3];
}

__global__ __launch_bounds__(512) void scan_partials_kernel(int* partials, int nb) {
  __shared__ int s[512];
  int t = threadIdx.x;
  s[t] = (t < nb) ? partials[t] : 0;
  __syncthreads();
  for (int off = 1; off < 512; off <<= 1) {
    int u = (t >= off) ? s[t - off] : 0;
    __syncthreads();
    s[t] += u;
    __syncthreads();
  }
  if (t < nb) partials[t] = (t == 0) ? 0 : s[t - 1];
}

__global__ __launch_bounds__(256) void final_scan_kernel(
    const int* __restrict__ deg, const int* __restrict__ partials,
    int* __restrict__ offsets, int n, int n_edges) {
  __shared__ int s[256];
  int t = threadIdx.x;
  int i = blockIdx.x * 256 + t;
  int v = (i < n) ? deg[i] : 0;
  s[t] = v;
  __syncthreads();
  for (int off = 1; off < 256; off <<= 1) {
    int u = (t >= off) ? s[t - off] : 0;
    __syncthreads();
    s[t] += u;
    __syncthreads();
  }
  int excl = s[t] - v + partials[blockIdx.x];
  if (i < n) offsets[i] = excl;
  if (i == 0) offsets[n] = n_edges;
}

__global__ __launch_bounds__(256) void bucket_init_kernel(
    const int* __restrict__ offsets, int* __restrict__ bucket_cursor) {
  int b = blockIdx.x * 256 + threadIdx.x;
  if (b < NBUCK) bucket_cursor[b] = offsets[b << 7];
}

__global__ __launch_bounds__(256) void bucket_partition_kernel(
    const int* __restrict__ src, const int* __restrict__ dst,
    int* __restrict__ bucket_cursor, int2* __restrict__ pairs, int n_edges) {
  __shared__ int hist[NBUCK];
  __shared__ int scan_[NBUCK];
  __shared__ int gbase[NBUCK];
  __shared__ int tmp[256];
  __shared__ int2 sorted[P1TILE];
  int t = threadIdx.x;
  long e0 = (long)blockIdx.x * P1TILE;
  int n = (int)min((long)P1TILE, (long)n_edges - e0);

  for (int b = t; b < NBUCK; b += 256) hist[b] = 0;
  __syncthreads();
  for (int i = t; i < n; i += 256) atomicAdd(&hist[dst[e0 + i] >> 7], 1);
  __syncthreads();

  int loc[4];
  int s = 0;
  #pragma unroll
  for (int j = 0; j < 4; ++j) {
    int idx = 4 * t + j;
    loc[j] = s;
    s += (idx < NBUCK) ? hist[idx] : 0;
  }
  tmp[t] = s;
  __syncthreads();
  for (int off = 1; off < 256; off <<= 1) {
    int u = (t >= off) ? tmp[t - off] : 0;
    __syncthreads();
    tmp[t] += u;
    __syncthreads();
  }
  int excl = tmp[t] - s;
  #pragma unroll
  for (int j = 0; j < 4; ++j) {
    int idx = 4 * t + j;
    if (idx < NBUCK) scan_[idx] = excl + loc[j];
  }
  __syncthreads();

  for (int b = t; b < NBUCK; b += 256) {
    int c = hist[b];
    gbase[b] = c ? atomicAdd(&bucket_cursor[b], c) : 0;
    hist[b] = scan_[b];
  }
  __syncthreads();

  for (int i = t; i < n; i += 256) {
    int sv = src[e0 + i];
    int dv = dst[e0 + i];
    int r = atomicAdd(&hist[dv >> 7], 1);   // LDS atomic
    sorted[r] = make_int2(sv, dv);
  }
  __syncthreads();

  for (int i = t; i < n; i += 256) {
    int2 p = sorted[i];
    int b = p.y >> 7;
    pairs[gbase[b] + (i - scan_[b])] = p;
  }
}

__global__ __launch_bounds__(256) void bucket_to_csr_kernel(
    const int2* __restrict__ pairs, const int* __restrict__ offsets,
    int* __restrict__ src_sorted, int n_nodes) {
  __shared__ int lcur[128];
  __shared__ int lout[MAXB];
  int b = blockIdx.x;
  int node0 = b << 7;
  int nend = min(node0 + 128, n_nodes);
  int t = threadIdx.x;
  int ebeg = offsets[node0];
  int eend = offsets[nend];
  int m = eend - ebeg;
  if (t < 128) {
    int node = node0 + t;
    lcur[t] = (node < n_nodes ? offsets[node] : eend) - ebeg;
  }
  __syncthreads();
  if (m <= MAXB) {
    for (int i = t; i < m; i += 256) {
      int2 p = pairs[ebeg + i];
      int r = atomicAdd(&lcur[p.y - node0], 1);  // LDS atomic
      lout[r] = p.x;
    }
    __syncthreads();
    for (int i = t; i < m; i += 256) src_sorted[ebeg + i] = lout[i];
  } else {
    for (int i = t; i < m; i += 256) {
      int2 p = pairs[ebeg + i];
      int r = atomicAdd(&lcur[p.y - node0], 1);
      src_sorted[ebeg + r] = p.x;
    }
  }
}

// ===========================================================================
// fp32 -> bf16 bulk convert (x -> xb), float4 in / ushort4 out.
// ===========================================================================
__global__ __launch_bounds__(256) void convert_bf16_kernel(
    const float* __restrict__ x, unsigned short* __restrict__ xb, int n4) {
  int i = blockIdx.x * 256 + threadIdx.x;
  if (i >= n4) return;
  float4 v = ((const float4*)x)[i];
  ushort4 o;
  o.x = f2bf(v.x); o.y = f2bf(v.y); o.z = f2bf(v.z); o.w = f2bf(v.w);
  ((ushort4*)xb)[i] = o;
}

// Transposed bf16 weights, n-major [128 n][128 k]:
//   Wt1[n][k] = n<64 ? w1_l[k][n] : w1_r[k][n-64]     (layer-1, K = in_dim)
//   Wt2[n][k] = k<64 ? w2_l[k][n] : w2_r[k-64][n]     (layer-2, K = [mean2|h])
__global__ __launch_bounds__(128) void prep_weights_kernel(
    const float* __restrict__ w1_l, const float* __restrict__ w1_r,
    const float* __restrict__ w2_l, const float* __restrict__ w2_r,
    unsigned short* __restrict__ Wt1, unsigned short* __restrict__ Wt2) {
  int n = blockIdx.x, k = threadIdx.x;
  float v1 = (n < 64) ? w1_l[k * 64 + n] : w1_r[k * 64 + (n - 64)];
  Wt1[n * 128 + k] = f2bf(v1);
  float v2 = (k < 64) ? w2_l[k * 128 + n] : w2_r[(k - 64) * 128 + n];
  Wt2[n * 128 + k] = f2bf(v2);
}

// ===========================================================================
// MFMA GEMM: Y[M][128] = A[M][128] @ Wt^T (+bias), A bf16, fp32 accum.
// Block: 256 thr = 4 waves, tile 64 rows x 128 cols; wave w owns cols
// [32w,32w+32).  A tile in LDS (row pad 128->136 bf16: 2-way alias = free).
// B fragment = one 16B load from n-major Wt (L2-hot, 32 KB).
// 32 MFMAs/wave, 8 independent per k-step.
// BIAS_MODE: 1 = bias[col-64] for col>=64 only (layer 1), 2 = bias[col].
// ===========================================================================
template <int BIAS_MODE, bool OUT_BF16>
__global__ __launch_bounds__(256) void mfma_gemm_kernel(
    const unsigned short* __restrict__ A, const unsigned short* __restrict__ Wt,
    const float* __restrict__ bias, void* __restrict__ Y, int M) {
  __shared__ unsigned short As[64 * 136];
  int node0 = blockIdx.x * 64;
  int t = threadIdx.x;
  #pragma unroll
  for (int i = 0; i < 4; ++i) {
    int c = t + i * 256;           // 1024 x 16B chunks
    int row = c >> 4, c8 = (c & 15) * 8;
    uint4 v = make_uint4(0u, 0u, 0u, 0u);
    if (node0 + row < M) v = *(const uint4*)&A[(long)(node0 + row) * 128 + c8];
    *(uint4*)&As[row * 136 + c8] = v;
  }
  __syncthreads();
  int w = t >> 6, lane = t & 63;
  int m = lane & 15, q = lane >> 4;
  int col0 = w * 32;
  floatx4 acc[4][2];
  #pragma unroll
  for (int rt = 0; rt < 4; ++rt)
    #pragma unroll
    for (int ct = 0; ct < 2; ++ct) acc[rt][ct] = (floatx4){0.f, 0.f, 0.f, 0.f};

  #pragma unroll
  for (int ks = 0; ks < 4; ++ks) {
    bf16x8 b0 = *(const bf16x8*)&Wt[(col0 + m) * 128 + ks * 32 + q * 8];
    bf16x8 b1 = *(const bf16x8*)&Wt[(col0 + 16 + m) * 128 + ks * 32 + q * 8];
    #pragma unroll
    for (int rt = 0; rt < 4; ++rt) {
      bf16x8 a = *(const bf16x8*)&As[(rt * 16 + m) * 136 + ks * 32 + q * 8];
      acc[rt][0] = __builtin_amdgcn_mfma_f32_16x16x32_bf16(a, b0, acc[rt][0], 0, 0, 0);
      acc[rt][1] = __builtin_amdgcn_mfma_f32_16x16x32_bf16(a, b1, acc[rt][1], 0, 0, 0);
    }
  }
  // C/D layout (m89-verified): col = lane&15, row = (lane>>4)*4 + reg
  #pragma unroll
  for (int ct = 0; ct < 2; ++ct) {
    int col = col0 + ct * 16 + m;
    float bv = 0.f;
    if (BIAS_MODE == 1) bv = (col >= 64) ? bias[col - 64] : 0.f;
    if (BIAS_MODE == 2) bv = bias[col];
    #pragma unroll
    for (int rt = 0; rt < 4; ++rt) {
      #pragma unroll
      for (int i = 0; i < 4; ++i) {
        int row = node0 + rt * 16 + q * 4 + i;
        if (row >= M) continue;
        float v = acc[rt][ct][i] + bv;
        if (OUT_BF16) ((unsigned short*)Y)[(long)row * 128 + col] = f2bf(v);
        else          ((float*)Y)[(long)row * 128 + col] = v;
      }
    }
  }
}

// ===========================================================================
// Gather-mean over bf16 rows (64 feats = 128 B).  One wave/node, 8 lanes x
// 16B per edge row -> 8 edges in flight; fp32 accumulation; shfl combine.
// FUSE_RELU: out = relu(mean + zadd_row) (layer-1 epilogue), bf16 out.
// ===========================================================================
template <bool FUSE_RELU>
__global__ __launch_bounds__(256) void aggregate_bf16_kernel(
    const unsigned short* __restrict__ gsrc, const unsigned short* __restrict__ zadd,
    unsigned short* __restrict__ outp, const int* __restrict__ offsets,
    const int* __restrict__ src_sorted, int n_nodes) {
  int wave = (blockIdx.x * 256 + threadIdx.x) >> 6;
  int lane = threadIdx.x & 63;
  if (wave >= n_nodes) return;
  int g = lane >> 3;    // edge slot 0..7
  int sl = lane & 7;    // 16B chunk within row
  int beg = offsets[wave], end = offsets[wave + 1];
  float acc[8] = {0.f, 0.f, 0.f, 0.f, 0.f, 0.f, 0.f, 0.f};
  for (int e = beg + g; e < end; e += 8) {
    int s = src_sorted[e];
    uint4 v = *(const uint4*)&gsrc[(long)s * 128 + sl * 8];
    acc[0] += __uint_as_float(v.x << 16);
    acc[1] += __uint_as_float(v.x & 0xffff0000u);
    acc[2] += __uint_as_float(v.y << 16);
    acc[3] += __uint_as_float(v.y & 0xffff0000u);
    acc[4] += __uint_as_float(v.z << 16);
    acc[5] += __uint_as_float(v.z & 0xffff0000u);
    acc[6] += __uint_as_float(v.w << 16);
    acc[7] += __uint_as_float(v.w & 0xffff0000u);
  }
  #pragma unroll
  for (int off = 8; off <= 32; off <<= 1) {
    #pragma unroll
    for (int j = 0; j < 8; ++j) acc[j] += __shfl_xor(acc[j], off, 64);
  }
  if (g == 0) {
    float inv = 1.f / fmaxf((float)(end - beg), 1.f);
    float r[8];
    #pragma unroll
    for (int j = 0; j < 8; ++j) r[j] = acc[j] * inv;
    if (FUSE_RELU) {
      uint4 z = *(const uint4*)&zadd[(long)wave * 128 + sl * 8];
      r[0] = fmaxf(r[0] + __uint_as_float(z.x << 16), 0.f);
      r[1] = fmaxf(r[1] + __uint_as_float(z.x & 0xffff0000u), 0.f);
      r[2] = fmaxf(r[2] + __uint_as_float(z.y << 16), 0.f);
      r[3] = fmaxf(r[3] + __uint_as_float(z.y & 0xffff0000u), 0.f);
      r[4] = fmaxf(r[4] + __uint_as_float(z.z << 16), 0.f);
      r[5] = fmaxf(r[5] + __uint_as_float(z.z & 0xffff0000u), 0.f);
      r[6] = fmaxf(r[6] + __uint_as_float(z.w << 16), 0.f);
      r[7] = fmaxf(r[7] + __uint_as_float(z.w & 0xffff0000u), 0.f);
    }
    uint4 ov;
    ov.x = (unsigned)f2bf(r[0]) | ((unsigned)f2bf(r[1]) << 16);
    ov.y = (unsigned)f2bf(r[2]) | ((unsigned)f2bf(r[3]) << 16);
    ov.z = (unsigned)f2bf(r[4]) | ((unsigned)f2bf(r[5]) << 16);
    ov.w = (unsigned)f2bf(r[6]) | ((unsigned)f2bf(r[7]) << 16);
    *(uint4*)&outp[(long)wave * 128 + sl * 8] = ov;
  }
}

extern "C" void kernel_launch(void* const* d_in, const int* in_sizes, int n_in,
                              void* d_out, int out_size, void* d_ws, size_t ws_size,
                              hipStream_t stream) {
  const float* x    = (const float*)d_in[0];
  const int*   ei   = (const int*)d_in[1];
  const float* w1_l = (const float*)d_in[2];
  const float* b1   = (const float*)d_in[3];
  const float* w1_r = (const float*)d_in[4];
  const float* w2_l = (const float*)d_in[5];
  const float* b2   = (const float*)d_in[6];
  const float* w2_r = (const float*)d_in[7];
  float* out = (float*)d_out;

  const int E = in_sizes[1] / 2;
  const int* src = ei;
  const int* dst = ei + E;

  // ---- workspace layout (~71.3 MB) ----
  unsigned short* ZB1 = (unsigned short*)d_ws;          // [N][128] bf16: y1|z1
  unsigned short* ZB2 = ZB1 + (long)N_NODES * 128;      // [N][128] bf16: xb, then mean2|h
  unsigned short* Wt1 = ZB2 + (long)N_NODES * 128;      // 128x128 bf16
  unsigned short* Wt2 = Wt1 + 16384;                    // 128x128 bf16
  int* deg           = (int*)(Wt2 + 16384);
  int* partials      = deg + N_NODES;                   // 512
  int* offsets       = partials + 512;                  // N+2 (padded even)
  int* bucket_cursor = offsets + N_NODES + 2;           // NBUCK (+pad)
  int* src_sorted    = bucket_cursor + NBUCK + 2;       // E
  int2* pairs        = (int2*)(src_sorted + E);         // E int2 (8B-aligned)

  int eb = (E + 255) / 256;

  // ---- CSR build ----
  hipMemsetAsync(deg, 0, (size_t)N_NODES * sizeof(int), stream);
  degree_kernel<<<eb, 256, 0, stream>>>(dst, deg, E);
  block_sums_kernel<<<SCAN_NB, 256, 0, stream>>>(deg, partials, N_NODES);
  scan_partials_kernel<<<1, 512, 0, stream>>>(partials, SCAN_NB);
  final_scan_kernel<<<SCAN_NB, 256, 0, stream>>>(deg, partials, offsets,
                                                 N_NODES, E);
  bucket_init_kernel<<<(NBUCK + 255) / 256, 256, 0, stream>>>(offsets,
                                                              bucket_cursor);
  bucket_partition_kernel<<<(E + P1TILE - 1) / P1TILE, 256, 0, stream>>>(
      src, dst, bucket_cursor, pairs, E);
  bucket_to_csr_kernel<<<NBUCK, 256, 0, stream>>>(pairs, offsets, src_sorted,
                                                  N_NODES);

  // ---- bf16 prep (overlappable with CSR chain in principle; same stream) ----
  convert_bf16_kernel<<<(N_NODES * 128 / 4 + 255) / 256, 256, 0, stream>>>(
      x, ZB2, N_NODES * 128 / 4);
  prep_weights_kernel<<<128, 128, 0, stream>>>(w1_l, w1_r, w2_l, w2_r, Wt1, Wt2);

  int gemm_blocks = (N_NODES + 63) / 64;
  int agg_blocks = (N_NODES + 3) / 4;

  // ---- Layer 1: ZB1 = [x@w1_l | x@w1_r + b1] (bf16) ----
  mfma_gemm_kernel<1, true><<<gemm_blocks, 256, 0, stream>>>(
      ZB2, Wt1, b1, ZB1, N_NODES);
  // h = relu(mean(y1) + z1) -> ZB2[:,64:128] (xb is dead; col-disjoint races: none)
  aggregate_bf16_kernel<true><<<agg_blocks, 256, 0, stream>>>(
      ZB1, ZB1 + 64, ZB2 + 64, offsets, src_sorted, N_NODES);

  // ---- Layer 2: mean2 -> ZB2[:,0:64]; out = [mean2|h] @ Wt2^T + b2 ----
  aggregate_bf16_kernel<false><<<agg_blocks, 256, 0, stream>>>(
      ZB2 + 64, nullptr, ZB2, offsets, src_sorted, N_NODES);
  mfma_gemm_kernel<2, false><<<gemm_blocks, 256, 0, stream>>>(
      ZB2, Wt2, b2, out, N_NODES);
}

// Round 6
// 310.795 us; speedup vs baseline: 14.9069x; 1.1719x over previous
//
#include <hip/hip_runtime.h>

#define N_NODES 100000
#define NBUCK   782      // ceil(100000/128) buckets of 128 nodes
#define P1TILE  8192     // edges per phase-1 block
#define MAXB    4096     // phase-2 LDS capacity (avg bucket = 2048 edges)

typedef __bf16 bf16x8 __attribute__((ext_vector_type(8)));
typedef float floatx4 __attribute__((ext_vector_type(4)));

static __device__ __forceinline__ unsigned short f2bf(float f) {
  unsigned u = __float_as_uint(f);
  u += 0x7fff + ((u >> 16) & 1);   // round-to-nearest-even
  return (unsigned short)(u >> 16);
}

// ===========================================================================
// Step 1: bucket-level edge counts (LDS histogram; ~200k global atomics on
// 3 KB instead of 1.6M on 400 KB -> no scattered-line write amplification).
// ===========================================================================
__global__ __launch_bounds__(256) void bucket_count_kernel(
    const int* __restrict__ dst, int* __restrict__ bucket_cnt, int n_edges) {
  __shared__ int hist[NBUCK];
  for (int b = threadIdx.x; b < NBUCK; b += 256) hist[b] = 0;
  __syncthreads();
  int stride = gridDim.x * 256;
  for (int e = blockIdx.x * 256 + threadIdx.x; e < n_edges; e += stride)
    atomicAdd(&hist[dst[e] >> 7], 1);
  __syncthreads();
  for (int b = threadIdx.x; b < NBUCK; b += 256) {
    int c = hist[b];
    if (c) atomicAdd(&bucket_cnt[b], c);
  }
}

// Step 2: exclusive scan of 782 bucket counts -> bucket_base, init cursors.
__global__ __launch_bounds__(256) void bucket_scan_kernel(
    const int* __restrict__ bucket_cnt, int* __restrict__ bucket_base,
    int* __restrict__ bucket_cursor) {
  __shared__ int tmp[256];
  int t = threadIdx.x;
  int loc[4];
  int s = 0;
  #pragma unroll
  for (int j = 0; j < 4; ++j) {
    int idx = 4 * t + j;
    loc[j] = s;
    s += (idx < NBUCK) ? bucket_cnt[idx] : 0;
  }
  tmp[t] = s;
  __syncthreads();
  for (int off = 1; off < 256; off <<= 1) {
    int u = (t >= off) ? tmp[t - off] : 0;
    __syncthreads();
    tmp[t] += u;
    __syncthreads();
  }
  int excl = tmp[t] - s;
  #pragma unroll
  for (int j = 0; j < 4; ++j) {
    int idx = 4 * t + j;
    if (idx < NBUCK) {
      int v = excl + loc[j];
      bucket_base[idx] = v;
      bucket_cursor[idx] = v;
    }
  }
  if (t == 255) bucket_base[NBUCK] = tmp[255];
}

// ===========================================================================
// Step 3: partition (src,dst) pairs into dst-buckets.  LDS histogram + scan
// + reorder per tile so same-bucket pairs leave as contiguous runs.
// ===========================================================================
__global__ __launch_bounds__(256) void bucket_partition_kernel(
    const int* __restrict__ src, const int* __restrict__ dst,
    int* __restrict__ bucket_cursor, int2* __restrict__ pairs, int n_edges) {
  __shared__ int hist[NBUCK];
  __shared__ int scan_[NBUCK];
  __shared__ int gbase[NBUCK];
  __shared__ int tmp[256];
  __shared__ int2 sorted[P1TILE];
  int t = threadIdx.x;
  long e0 = (long)blockIdx.x * P1TILE;
  int n = (int)min((long)P1TILE, (long)n_edges - e0);

  for (int b = t; b < NBUCK; b += 256) hist[b] = 0;
  __syncthreads();
  for (int i = t; i < n; i += 256) atomicAdd(&hist[dst[e0 + i] >> 7], 1);
  __syncthreads();

  int loc[4];
  int s = 0;
  #pragma unroll
  for (int j = 0; j < 4; ++j) {
    int idx = 4 * t + j;
    loc[j] = s;
    s += (idx < NBUCK) ? hist[idx] : 0;
  }
  tmp[t] = s;
  __syncthreads();
  for (int off = 1; off < 256; off <<= 1) {
    int u = (t >= off) ? tmp[t - off] : 0;
    __syncthreads();
    tmp[t] += u;
    __syncthreads();
  }
  int excl = tmp[t] - s;
  #pragma unroll
  for (int j = 0; j < 4; ++j) {
    int idx = 4 * t + j;
    if (idx < NBUCK) scan_[idx] = excl + loc[j];
  }
  __syncthreads();

  for (int b = t; b < NBUCK; b += 256) {
    int c = hist[b];
    gbase[b] = c ? atomicAdd(&bucket_cursor[b], c) : 0;
    hist[b] = scan_[b];
  }
  __syncthreads();

  for (int i = t; i < n; i += 256) {
    int sv = src[e0 + i];
    int dv = dst[e0 + i];
    int r = atomicAdd(&hist[dv >> 7], 1);   // LDS atomic
    sorted[r] = make_int2(sv, dv);
  }
  __syncthreads();

  for (int i = t; i < n; i += 256) {
    int2 p = sorted[i];
    int b = p.y >> 7;
    pairs[gbase[b] + (i - scan_[b])] = p;
  }
}

// ===========================================================================
// Step 4 (merged): per bucket, build node-level CSR offsets from the bucket's
// own pairs (LDS histogram + 128-entry scan -> coalesced offsets write) and
// sort src values by node into src_sorted (LDS staging, coalesced stream-out).
// ===========================================================================
__global__ __launch_bounds__(256) void bucket_csr_kernel(
    const int2* __restrict__ pairs, const int* __restrict__ bucket_base,
    int* __restrict__ offsets, int* __restrict__ src_sorted,
    int n_nodes, int n_edges) {
  __shared__ int2 sp[MAXB];
  __shared__ int lout[MAXB];
  __shared__ int ndeg[128];
  __shared__ int nsc[128];
  int b = blockIdx.x;
  int node0 = b << 7;
  int t = threadIdx.x;
  int ebeg = bucket_base[b];
  int eend = bucket_base[b + 1];
  int m = eend - ebeg;
  bool fits = (m <= MAXB);
  if (t < 128) ndeg[t] = 0;
  __syncthreads();

  // histogram over the bucket's 128 nodes
  if (fits) {
    for (int i = t; i < m; i += 256) {
      int2 p = pairs[ebeg + i];
      sp[i] = p;
      atomicAdd(&ndeg[p.y & 127], 1);   // LDS atomic
    }
  } else {  // overflow fallback (statistically never: avg 2048, cap 4096)
    for (int i = t; i < m; i += 256)
      atomicAdd(&ndeg[pairs[ebeg + i].y & 127], 1);
  }
  __syncthreads();

  // exclusive scan of 128 node degrees
  if (t < 128) nsc[t] = ndeg[t];
  __syncthreads();
  for (int off = 1; off < 128; off <<= 1) {
    int u = 0;
    if (t < 128 && t >= off) u = nsc[t - off];
    __syncthreads();
    if (t < 128) nsc[t] += u;
    __syncthreads();
  }
  if (t < 128) {
    int excl = nsc[t] - ndeg[t];
    int node = node0 + t;
    if (node < n_nodes) offsets[node] = ebeg + excl;
    ndeg[t] = excl;   // repurpose as placement cursor
  }
  if (b == NBUCK - 1 && t == 0) offsets[n_nodes] = n_edges;
  __syncthreads();

  // place src values grouped by node, stream out coalesced
  if (fits) {
    for (int i = t; i < m; i += 256) {
      int2 p = sp[i];
      int r = atomicAdd(&ndeg[p.y & 127], 1);  // LDS atomic
      lout[r] = p.x;
    }
    __syncthreads();
    for (int i = t; i < m; i += 256) src_sorted[ebeg + i] = lout[i];
  } else {
    for (int i = t; i < m; i += 256) {
      int2 p = pairs[ebeg + i];
      int r = atomicAdd(&ndeg[p.y & 127], 1);
      src_sorted[ebeg + r] = p.x;
    }
  }
}

// ===========================================================================
// fp32 -> bf16 bulk convert (x -> xb), float4 in / ushort4 out.
// ===========================================================================
__global__ __launch_bounds__(256) void convert_bf16_kernel(
    const float* __restrict__ x, unsigned short* __restrict__ xb, int n4) {
  int i = blockIdx.x * 256 + threadIdx.x;
  if (i >= n4) return;
  float4 v = ((const float4*)x)[i];
  ushort4 o;
  o.x = f2bf(v.x); o.y = f2bf(v.y); o.z = f2bf(v.z); o.w = f2bf(v.w);
  ((ushort4*)xb)[i] = o;
}

// Transposed bf16 weights, n-major [128 n][128 k]:
//   Wt1[n][k] = n<64 ? w1_l[k][n] : w1_r[k][n-64]     (layer-1, K = in_dim)
//   Wt2[n][k] = k<64 ? w2_l[k][n] : w2_r[k-64][n]     (layer-2, K = [mean2|h])
__global__ __launch_bounds__(128) void prep_weights_kernel(
    const float* __restrict__ w1_l, const float* __restrict__ w1_r,
    const float* __restrict__ w2_l, const float* __restrict__ w2_r,
    unsigned short* __restrict__ Wt1, unsigned short* __restrict__ Wt2) {
  int n = blockIdx.x, k = threadIdx.x;
  float v1 = (n < 64) ? w1_l[k * 64 + n] : w1_r[k * 64 + (n - 64)];
  Wt1[n * 128 + k] = f2bf(v1);
  float v2 = (k < 64) ? w2_l[k * 128 + n] : w2_r[(k - 64) * 128 + n];
  Wt2[n * 128 + k] = f2bf(v2);
}

// ===========================================================================
// MFMA GEMM: Y[M][128] = A[M][128] @ Wt^T (+bias), A bf16, fp32 accum.
// Block: 256 thr = 4 waves, tile 64 rows x 128 cols; wave w owns cols
// [32w,32w+32).  A tile in LDS (row pad 128->136 bf16: 2-way alias = free).
// BIAS_MODE: 1 = bias[col-64] for col>=64 only (layer 1), 2 = bias[col].
// ===========================================================================
template <int BIAS_MODE, bool OUT_BF16>
__global__ __launch_bounds__(256) void mfma_gemm_kernel(
    const unsigned short* __restrict__ A, const unsigned short* __restrict__ Wt,
    const float* __restrict__ bias, void* __restrict__ Y, int M) {
  __shared__ unsigned short As[64 * 136];
  int node0 = blockIdx.x * 64;
  int t = threadIdx.x;
  #pragma unroll
  for (int i = 0; i < 4; ++i) {
    int c = t + i * 256;           // 1024 x 16B chunks
    int row = c >> 4, c8 = (c & 15) * 8;
    uint4 v = make_uint4(0u, 0u, 0u, 0u);
    if (node0 + row < M) v = *(const uint4*)&A[(long)(node0 + row) * 128 + c8];
    *(uint4*)&As[row * 136 + c8] = v;
  }
  __syncthreads();
  int w = t >> 6, lane = t & 63;
  int m = lane & 15, q = lane >> 4;
  int col0 = w * 32;
  floatx4 acc[4][2];
  #pragma unroll
  for (int rt = 0; rt < 4; ++rt)
    #pragma unroll
    for (int ct = 0; ct < 2; ++ct) acc[rt][ct] = (floatx4){0.f, 0.f, 0.f, 0.f};

  #pragma unroll
  for (int ks = 0; ks < 4; ++ks) {
    bf16x8 b0 = *(const bf16x8*)&Wt[(col0 + m) * 128 + ks * 32 + q * 8];
    bf16x8 b1 = *(const bf16x8*)&Wt[(col0 + 16 + m) * 128 + ks * 32 + q * 8];
    #pragma unroll
    for (int rt = 0; rt < 4; ++rt) {
      bf16x8 a = *(const bf16x8*)&As[(rt * 16 + m) * 136 + ks * 32 + q * 8];
      acc[rt][0] = __builtin_amdgcn_mfma_f32_16x16x32_bf16(a, b0, acc[rt][0], 0, 0, 0);
      acc[rt][1] = __builtin_amdgcn_mfma_f32_16x16x32_bf16(a, b1, acc[rt][1], 0, 0, 0);
    }
  }
  // C/D layout (m89-verified): col = lane&15, row = (lane>>4)*4 + reg
  #pragma unroll
  for (int ct = 0; ct < 2; ++ct) {
    int col = col0 + ct * 16 + m;
    float bv = 0.f;
    if (BIAS_MODE == 1) bv = (col >= 64) ? bias[col - 64] : 0.f;
    if (BIAS_MODE == 2) bv = bias[col];
    #pragma unroll
    for (int rt = 0; rt < 4; ++rt) {
      #pragma unroll
      for (int i = 0; i < 4; ++i) {
        int row = node0 + rt * 16 + q * 4 + i;
        if (row >= M) continue;
        float v = acc[rt][ct][i] + bv;
        if (OUT_BF16) ((unsigned short*)Y)[(long)row * 128 + col] = f2bf(v);
        else          ((float*)Y)[(long)row * 128 + col] = v;
      }
    }
  }
}

// ===========================================================================
// Gather-mean over bf16 rows (64 feats = 128 B).  One wave/node, 8 lanes x
// 16B per edge row -> 8 edges in flight; fp32 accumulation; shfl combine.
// FUSE_RELU: out = relu(mean + zadd_row) (layer-1 epilogue), bf16 out.
// ===========================================================================
template <bool FUSE_RELU>
__global__ __launch_bounds__(256) void aggregate_bf16_kernel(
    const unsigned short* __restrict__ gsrc, const unsigned short* __restrict__ zadd,
    unsigned short* __restrict__ outp, const int* __restrict__ offsets,
    const int* __restrict__ src_sorted, int n_nodes) {
  int wave = (blockIdx.x * 256 + threadIdx.x) >> 6;
  int lane = threadIdx.x & 63;
  if (wave >= n_nodes) return;
  int g = lane >> 3;    // edge slot 0..7
  int sl = lane & 7;    // 16B chunk within row
  int beg = offsets[wave], end = offsets[wave + 1];
  float acc[8] = {0.f, 0.f, 0.f, 0.f, 0.f, 0.f, 0.f, 0.f};
  for (int e = beg + g; e < end; e += 8) {
    int s = src_sorted[e];
    uint4 v = *(const uint4*)&gsrc[(long)s * 128 + sl * 8];
    acc[0] += __uint_as_float(v.x << 16);
    acc[1] += __uint_as_float(v.x & 0xffff0000u);
    acc[2] += __uint_as_float(v.y << 16);
    acc[3] += __uint_as_float(v.y & 0xffff0000u);
    acc[4] += __uint_as_float(v.z << 16);
    acc[5] += __uint_as_float(v.z & 0xffff0000u);
    acc[6] += __uint_as_float(v.w << 16);
    acc[7] += __uint_as_float(v.w & 0xffff0000u);
  }
  #pragma unroll
  for (int off = 8; off <= 32; off <<= 1) {
    #pragma unroll
    for (int j = 0; j < 8; ++j) acc[j] += __shfl_xor(acc[j], off, 64);
  }
  if (g == 0) {
    float inv = 1.f / fmaxf((float)(end - beg), 1.f);
    float r[8];
    #pragma unroll
    for (int j = 0; j < 8; ++j) r[j] = acc[j] * inv;
    if (FUSE_RELU) {
      uint4 z = *(const uint4*)&zadd[(long)wave * 128 + sl * 8];
      r[0] = fmaxf(r[0] + __uint_as_float(z.x << 16), 0.f);
      r[1] = fmaxf(r[1] + __uint_as_float(z.x & 0xffff0000u), 0.f);
      r[2] = fmaxf(r[2] + __uint_as_float(z.y << 16), 0.f);
      r[3] = fmaxf(r[3] + __uint_as_float(z.y & 0xffff0000u), 0.f);
      r[4] = fmaxf(r[4] + __uint_as_float(z.z << 16), 0.f);
      r[5] = fmaxf(r[5] + __uint_as_float(z.z & 0xffff0000u), 0.f);
      r[6] = fmaxf(r[6] + __uint_as_float(z.w << 16), 0.f);
      r[7] = fmaxf(r[7] + __uint_as_float(z.w & 0xffff0000u), 0.f);
    }
    uint4 ov;
    ov.x = (unsigned)f2bf(r[0]) | ((unsigned)f2bf(r[1]) << 16);
    ov.y = (unsigned)f2bf(r[2]) | ((unsigned)f2bf(r[3]) << 16);
    ov.z = (unsigned)f2bf(r[4]) | ((unsigned)f2bf(r[5]) << 16);
    ov.w = (unsigned)f2bf(r[6]) | ((unsigned)f2bf(r[7]) << 16);
    *(uint4*)&outp[(long)wave * 128 + sl * 8] = ov;
  }
}

extern "C" void kernel_launch(void* const* d_in, const int* in_sizes, int n_in,
                              void* d_out, int out_size, void* d_ws, size_t ws_size,
                              hipStream_t stream) {
  const float* x    = (const float*)d_in[0];
  const int*   ei   = (const int*)d_in[1];
  const float* w1_l = (const float*)d_in[2];
  const float* b1   = (const float*)d_in[3];
  const float* w1_r = (const float*)d_in[4];
  const float* w2_l = (const float*)d_in[5];
  const float* b2   = (const float*)d_in[6];
  const float* w2_r = (const float*)d_in[7];
  float* out = (float*)d_out;

  const int E = in_sizes[1] / 2;
  const int* src = ei;
  const int* dst = ei + E;

  // ---- workspace layout (~70.9 MB) ----
  unsigned short* ZB1 = (unsigned short*)d_ws;          // [N][128] bf16: y1|z1
  unsigned short* ZB2 = ZB1 + (long)N_NODES * 128;      // [N][128] bf16: xb, then mean2|h
  unsigned short* Wt1 = ZB2 + (long)N_NODES * 128;      // 128x128 bf16
  unsigned short* Wt2 = Wt1 + 16384;                    // 128x128 bf16
  int* bucket_cnt    = (int*)(Wt2 + 16384);             // 782 (even)
  int* bucket_base   = bucket_cnt + NBUCK;              // 784 (padded even)
  int* bucket_cursor = bucket_base + NBUCK + 2;         // 784 (padded even)
  int* offsets       = bucket_cursor + NBUCK + 2;       // N+2 (even)
  int* src_sorted    = offsets + N_NODES + 2;           // E (even)
  int2* pairs        = (int2*)(src_sorted + E);         // E int2 (8B-aligned)

  // ---- CSR build (bucketed; no node-level global atomics anywhere) ----
  hipMemsetAsync(bucket_cnt, 0, (size_t)NBUCK * sizeof(int), stream);
  bucket_count_kernel<<<512, 256, 0, stream>>>(dst, bucket_cnt, E);
  bucket_scan_kernel<<<1, 256, 0, stream>>>(bucket_cnt, bucket_base,
                                            bucket_cursor);
  bucket_partition_kernel<<<(E + P1TILE - 1) / P1TILE, 256, 0, stream>>>(
      src, dst, bucket_cursor, pairs, E);
  bucket_csr_kernel<<<NBUCK, 256, 0, stream>>>(pairs, bucket_base, offsets,
                                               src_sorted, N_NODES, E);

  // ---- bf16 prep ----
  convert_bf16_kernel<<<(N_NODES * 128 / 4 + 255) / 256, 256, 0, stream>>>(
      x, ZB2, N_NODES * 128 / 4);
  prep_weights_kernel<<<128, 128, 0, stream>>>(w1_l, w1_r, w2_l, w2_r, Wt1, Wt2);

  int gemm_blocks = (N_NODES + 63) / 64;
  int agg_blocks = (N_NODES + 3) / 4;

  // ---- Layer 1: ZB1 = [x@w1_l | x@w1_r + b1] (bf16) ----
  mfma_gemm_kernel<1, true><<<gemm_blocks, 256, 0, stream>>>(
      ZB2, Wt1, b1, ZB1, N_NODES);
  // h = relu(mean(y1) + z1) -> ZB2[:,64:128] (xb dead after GEMM1)
  aggregate_bf16_kernel<true><<<agg_blocks, 256, 0, stream>>>(
      ZB1, ZB1 + 64, ZB2 + 64, offsets, src_sorted, N_NODES);

  // ---- Layer 2: mean2 -> ZB2[:,0:64]; out = [mean2|h] @ Wt2^T + b2 ----
  aggregate_bf16_kernel<false><<<agg_blocks, 256, 0, stream>>>(
      ZB2 + 64, nullptr, ZB2, offsets, src_sorted, N_NODES);
  mfma_gemm_kernel<2, false><<<gemm_blocks, 256, 0, stream>>>(
      ZB2, Wt2, b2, out, N_NODES);
}